// Round 14
// baseline (7518.796 us; speedup 1.0000x reference)
//
#include <hip/hip_runtime.h>
#include <hip/hip_bf16.h>

// PhasedLSTM classifier: persistent cooperative kernel (R9 dataflow, split-path
// gating). 8 groups (32 samples) x 32 slices = 256 blocks (1/CU), 6 waves.
// Per round: wave0 {poll flag0 -> tok0 -> DMA h0.lo}; wave1 {tok0 -> DMA h0.hi};
// wave2 {poll flag1 -> tok1 -> DMA h1.lo}; wave3 {tok1 -> DMA h1.hi};
// wave4 {x/t prefetch}; wave5 {tok0&tok1 -> LN stats}; STAGE-BAR; MFMA(all);
// Z-BAR; combine L0(waves0-3) || L1(waves4-5); per-side drain+arrival;
// wave3 posts flag0 early, wave5 posts flag1; head on wave1. 2 barriers/round.
// Exchange semantics: relaxed agent-scope atomics + G2L(aux=16) (proven R9).
// Round r computes L0 step r, L1 step r-1, head step r-2.

#define NB 256
#define NTHR 384
#define T_STEPS 500
#define RON 0.05f
#define ALPHA_LEAK 1e-3f

typedef short short8 __attribute__((ext_vector_type(8)));
typedef float f32x4 __attribute__((ext_vector_type(4)));
typedef unsigned long long ull;

// ---------------- ws layout (bytes) ----------------
#define OFF_WSWZ 0u              // 6291456  swizzled bf16 weights
#define OFF_U1   6291456u        // 8192
#define OFF_V1   6299648u        // 8192
#define OFF_WFP  6307840u        // 20480    Wf' permuted [kk][c][lane] f32
#define OFF_UFV  6328320u        // 128
#define OFF_H0B  6328448u        // 524288   [2][8][16384] bf16, frag order
#define OFF_H1B  6852736u        // 524288
#define OFF_ST0  7377024u        // 131072   [2][8][32 m][32 sl][2] f32
#define OFF_ST1  7508096u        // 131072
#define OFF_FLG0 7639168u        // 1024     [8][32] u32 round flags (L0/h0)
#define OFF_FLG1 7640192u        // 1024     [8][32] u32 round flags (L1/h1)
#define ZERO_BYTES 1312768u

// ---------------- LDS layout (bytes) ----------------
// 0      h0b            32768
// 32768  h1bL[2]        65536
// 98304  zbv            25728   (3 x [32][67] f32)
// 124032 mus              512   (mu0,rs0,mu1,rs1 x 32)
// 124544 xtb              640   (x0..x2,t x32 + t1 x32)
// 125184 prm             2048
// 127232 wfl            20480   ([kk][c][64] f32, conflict-free)
// 147712 ufl              128
// 147840 tok[4]            16   (tok0,tok1,arr0,arr1)
#define SMEM_BYTES 147968

#define AT_LD(p)    __hip_atomic_load((p), __ATOMIC_RELAXED, __HIP_MEMORY_SCOPE_AGENT)
#define AT_ST(p, v) __hip_atomic_store((p), (v), __ATOMIC_RELAXED, __HIP_MEMORY_SCOPE_AGENT)
#define LDS_ADD(p)  __hip_atomic_fetch_add((p), 1u, __ATOMIC_RELEASE, __HIP_MEMORY_SCOPE_WORKGROUP)
#define LDS_LD(p)   __hip_atomic_load((p), __ATOMIC_ACQUIRE, __HIP_MEMORY_SCOPE_WORKGROUP)
#define LDS_ST(p,v) __hip_atomic_store((p), (v), __ATOMIC_RELEASE, __HIP_MEMORY_SCOPE_WORKGROUP)

#define G2L(gp, lp) \
  __builtin_amdgcn_global_load_lds( \
      (const __attribute__((address_space(1))) void*)(gp), \
      (__attribute__((address_space(3))) void*)(lp), 16, 0, 16)

__device__ __forceinline__ short f2bf(float x) {
  unsigned u = __float_as_uint(x);
  unsigned r = (u + 0x7fffu + ((u >> 16) & 1u)) >> 16;
  return (short)r;
}
__device__ __forceinline__ float bf2f(short s) {
  return __uint_as_float(((unsigned)(unsigned short)s) << 16);
}
__device__ __forceinline__ float sigm(float x) { return 1.f / (1.f + __expf(-x)); }
__device__ __forceinline__ float tanh_f(float x) {
  float cx = fminf(fmaxf(x, -15.f), 15.f);
  float e = __expf(2.f * cx);
  return (e - 1.f) / (e + 1.f);
}
__device__ __forceinline__ float timegate(float t, float tau, float s) {
  float phi = fmodf(t - s, tau);
  if (phi < 0.f) phi += tau;
  phi /= tau;
  return phi < 0.5f * RON ? (2.f / RON) * phi
       : (phi < RON ? 2.f - (2.f / RON) * phi : ALPHA_LEAK * phi);
}
// element index (shorts) of (sample m<32, unit k) in a [32][512] bf16 buffer
// stored in 16x16x32-MFMA A-fragment order.
__device__ __forceinline__ int fragidx(int m, int k) {
  return ((((k >> 5) * 2 + (m >> 4)) * 64) + (((k >> 3) & 3) * 16) + (m & 15)) * 8 + (k & 7);
}

// ---------------- prep kernels ----------------
__global__ void prep_weights(const float* __restrict__ R0, const float* __restrict__ W1,
                             const float* __restrict__ R1, const float* __restrict__ g0,
                             short* __restrict__ Wswz) {
  int t = blockIdx.x * 256 + threadIdx.x;   // < 393216
  int lane = t & 63; int rest = t >> 6;
  int nf = rest & 1;  rest >>= 1;
  int kb = rest & 15; rest >>= 4;
  int ch = rest & 1;  rest >>= 1;
  int mm = rest % 3;  int slice = rest / 3;
  int c = ch * 32 + nf * 16 + (lane & 15);
  int gate = c >> 4;
  int unit = slice * 16 + (c & 15);
  int gcol = gate * 512 + unit;
  int k0 = kb * 32 + (lane >> 4) * 8;
  const float* src = (mm == 0) ? R0 : (mm == 1 ? W1 : R1);
  short8 o;
  #pragma unroll
  for (int e = 0; e < 8; ++e) {
    float v = src[(size_t)(k0 + e) * 2048 + gcol];
    if (mm == 1) v *= g0[k0 + e];
    o[e] = f2bf(v);
  }
  *(short8*)(Wswz + (size_t)t * 8) = o;
}

__global__ void prep_vecs(const float* __restrict__ W1, const float* __restrict__ g0,
                          const float* __restrict__ be0,
                          float* __restrict__ u1, float* __restrict__ v1) {
  int c = blockIdx.x * 256 + threadIdx.x;  // < 2048
  float su = 0.f, sv = 0.f;
  for (int k = 0; k < 512; ++k) {
    float w = W1[(size_t)k * 2048 + c];
    su += be0[k] * w; sv += g0[k] * w;
  }
  u1[c] = su; v1[c] = sv;
}

__global__ void prep_head(const float* __restrict__ Wf, const float* __restrict__ g1,
                          const float* __restrict__ be1, const float* __restrict__ bfv,
                          float* __restrict__ Wfp, float* __restrict__ ufv) {
  int t = blockIdx.x * 256 + threadIdx.x;
  if (t < 5120) {
    int kk = t / 640, rem = t - kk * 640, c = rem >> 6, l = rem & 63;
    int k = 8 * l + kk;
    Wfp[t] = g1[k] * Wf[k * 10 + c];
  }
  if (t < 10) {
    float su = bfv[t], sv = 0.f;
    for (int k = 0; k < 512; ++k) {
      float w = Wf[k * 10 + t];
      su += be1[k] * w; sv += g1[k] * w;
    }
    ufv[t] = su; ufv[16 + t] = sv;
  }
}

// ---------------- persistent kernel ----------------
struct Ptrs {
  const float *x, *times, *W0, *b0, *tau0, *s0, *b1, *tau1, *s1;
  const float *u1v, *v1v, *Wfp, *ufv;
  short *H0b, *H1b;
  float *St0, *St1;
  unsigned *flag0, *flag1;
  float *out;
};

__launch_bounds__(NTHR, 1)
__global__ void plstm_persist(Ptrs P, const short* __restrict__ Wswz) {
  extern __shared__ char smem[];
  short* h0b  = (short*)smem;
  short* h1bL = (short*)(smem + 32768);
  float* zbv  = (float*)(smem + 98304);
  float* mus  = (float*)(smem + 124032);
  float* xtb  = (float*)(smem + 124544);
  float* prm  = (float*)(smem + 125184);
  float* wfl  = (float*)(smem + 127232);
  float* ufl  = (float*)(smem + 147712);
  unsigned* tok = (unsigned*)(smem + 147840);  // tok0,tok1,arr0,arr1

  const int tid = threadIdx.x;
  const int g = blockIdx.x & 7;
  const int slice = blockIdx.x >> 3;
  const int wid = tid >> 6, lane = tid & 63;
  const int mm = wid >> 1, ch = wid & 1;
  const int gm0 = g * 32;

  // ---- one-time LDS init ----
  if (tid < 4) tok[tid] = 0u;
  for (int i = tid; i < 512; i += NTHR) {
    float v;
    if (i < 192)      { int f = i >> 6, c = i & 63; v = P.W0[f * 2048 + ((c >> 4) << 9) + slice * 16 + (c & 15)]; }
    else if (i < 256) { int c = i & 63; v = P.b0[((c >> 4) << 9) + slice * 16 + (c & 15)]; }
    else if (i < 320) { int c = i & 63; int gc = ((c >> 4) << 9) + slice * 16 + (c & 15);
                        v = P.b1[gc] + P.u1v[gc]; }
    else if (i < 384) { int c = i & 63; v = P.v1v[((c >> 4) << 9) + slice * 16 + (c & 15)]; }
    else if (i < 448) v = 0.f;
    else if (i < 464) v = P.tau0[slice * 16 + (i & 15)];
    else if (i < 480) v = P.s0[slice * 16 + (i & 15)];
    else if (i < 496) v = P.tau1[slice * 16 + (i & 15)];
    else              v = P.s1[slice * 16 + (i & 15)];
    prm[i] = v;
  }
  for (int i = tid; i < 5120; i += NTHR) wfl[i] = P.Wfp[i];
  if (tid < 32) ufl[tid] = P.ufv[tid];

  // ---- resident weights: 16 kb x 2 nf x short8 = 128 VGPRs ----
  short8 wr[16][2];
  {
    const short* wb = Wswz + ((((size_t)slice * 3 + mm) * 2 + ch) * 32 * 64) * 8;
    #pragma unroll
    for (int kb = 0; kb < 16; ++kb)
      #pragma unroll
      for (int nf = 0; nf < 2; ++nf) {
        wr[kb][nf] = *(const short8*)(wb + ((kb * 2 + nf) * 64 + lane) * 8);
        asm volatile("" : "+v"(wr[kb][nf]));   // value barrier vs remat
      }
  }
  // register-resident recurrent state
  float h0A0 = 0.f, h0A1 = 0.f, c0A0 = 0.f, c0A1 = 0.f;     // tid<256: L0 item tid
  float h1S[4] = {0.f, 0.f, 0.f, 0.f};                      // tid>=256: L1 sample m=t>>2,
  float c1S[4] = {0.f, 0.f, 0.f, 0.f};                      //   units 4j..4j+3 (j=t&3)
  __syncthreads();

  for (int r = 0; r <= T_STEPS + 1; ++r) {
    const int bufA = (r + 1) & 1;
    const int bufB = r & 1;
    short* h1s = h1bL + bufB * 16384;

    // ---- pre-stage: per-wave gated poll + DMA/stats/prefetch ----
    if (wid == 0) {
      { const unsigned tgt = (unsigned)r;
        const unsigned* fp = P.flag0 + g * 32 + (lane & 31);
        for (int it_ = 0; it_ < 200000; ++it_) {
          unsigned v = (lane < 32) ? AT_LD(fp) : 0xFFFFFFFFu;
          if (__all((int)(v >= tgt))) break;
          __builtin_amdgcn_s_sleep(1);
        } }
      if (lane == 0) LDS_ST(&tok[0], (unsigned)(r + 1));
      const char* gA = (const char*)(P.H0b + ((size_t)bufA * 8 + g) * 16384);
      char* lA = (char*)h0b;
      #pragma unroll
      for (int j = 0; j < 16; ++j) {
        unsigned off = (unsigned)(j * 64 + lane) * 16u;
        G2L(gA + off, lA + off);
      }
    } else if (wid == 1) {
      { const unsigned tgt = (unsigned)(r + 1);
        for (int it_ = 0; it_ < 2000000; ++it_) {
          if (LDS_LD(&tok[0]) >= tgt) break;
          __builtin_amdgcn_s_sleep(1);
        } }
      const char* gA = (const char*)(P.H0b + ((size_t)bufA * 8 + g) * 16384) + 16384;
      char* lA = (char*)h0b + 16384;
      #pragma unroll
      for (int j = 0; j < 16; ++j) {
        unsigned off = (unsigned)(j * 64 + lane) * 16u;
        G2L(gA + off, lA + off);
      }
    } else if (wid == 2) {
      { const unsigned tgt = (unsigned)((r >= 2) ? r : 0);
        const unsigned* fp = P.flag1 + g * 32 + (lane & 31);
        for (int it_ = 0; it_ < 200000; ++it_) {
          unsigned v = (lane < 32) ? AT_LD(fp) : 0xFFFFFFFFu;
          if (__all((int)(v >= tgt))) break;
          __builtin_amdgcn_s_sleep(1);
        } }
      if (lane == 0) LDS_ST(&tok[1], (unsigned)(r + 1));
      const char* gB = (const char*)(P.H1b + ((size_t)bufB * 8 + g) * 16384);
      char* lB = (char*)h1s;
      #pragma unroll
      for (int j = 0; j < 16; ++j) {
        unsigned off = (unsigned)(j * 64 + lane) * 16u;
        G2L(gB + off, lB + off);
      }
    } else if (wid == 3) {
      { const unsigned tgt = (unsigned)(r + 1);
        for (int it_ = 0; it_ < 2000000; ++it_) {
          if (LDS_LD(&tok[1]) >= tgt) break;
          __builtin_amdgcn_s_sleep(1);
        } }
      const char* gB = (const char*)(P.H1b + ((size_t)bufB * 8 + g) * 16384) + 16384;
      char* lB = (char*)h1s + 16384;
      #pragma unroll
      for (int j = 0; j < 16; ++j) {
        unsigned off = (unsigned)(j * 64 + lane) * 16u;
        G2L(gB + off, lB + off);
      }
    } else if (wid == 4) {
      int m = lane & 31;
      if (lane < 32) {
        int step = (r < T_STEPS) ? r : (T_STEPS - 1);
        const float* xp = P.x + ((size_t)(gm0 + m) * T_STEPS + step) * 3;
        xtb[m * 4 + 0] = xp[0];
        xtb[m * 4 + 1] = xp[1];
        xtb[m * 4 + 2] = xp[2];
        xtb[m * 4 + 3] = P.times[(size_t)(gm0 + m) * T_STEPS + step];
      } else {
        int s1_ = (r >= 1) ? (r - 1) : 0;
        if (s1_ > T_STEPS - 1) s1_ = T_STEPS - 1;
        xtb[128 + m] = P.times[(size_t)(gm0 + m) * T_STEPS + s1_];
      }
    } else {   // wid == 5: stats, gated on both tokens
      { const unsigned tgt = (unsigned)(r + 1);
        for (int it_ = 0; it_ < 2000000; ++it_) {
          if (LDS_LD(&tok[0]) >= tgt && LDS_LD(&tok[1]) >= tgt) break;
          __builtin_amdgcn_s_sleep(1);
        } }
      const int layer = lane >> 5, m = lane & 31;
      const float* base = layer ? (P.St1 + ((size_t)bufB * 8 + g) * 2048 + m * 64)
                                : (P.St0 + ((size_t)bufA * 8 + g) * 2048 + m * 64);
      const ull* bu = (const ull*)base;
      float s_ = 0.f, q_ = 0.f;
      #pragma unroll
      for (int sl = 0; sl < 32; ++sl) {
        ull v = AT_LD(bu + sl);
        s_ += __uint_as_float((unsigned)v);
        q_ += __uint_as_float((unsigned)(v >> 32));
      }
      float mu = s_ * (1.f / 512.f);
      float var = q_ * (1.f / 512.f) - mu * mu;
      mus[layer * 64 + m] = mu;
      mus[layer * 64 + 32 + m] = rsqrtf(var + 1e-3f);
    }
    __syncthreads();                     // STAGE-BAR: DMA drained, stats ready
    float m1r = 0.f, r1r = 0.f;
    if (wid == 1) { m1r = mus[64 + slice]; r1r = mus[96 + slice]; }  // hoist

    // ---- MFMA: z-slice = A @ Wslice (all 6 waves) ----
    if (r <= T_STEPS) {
      f32x4 acc[2][2] = {};
      const short* asrc = (mm == 2) ? h1s : h0b;
      #pragma unroll
      for (int kb = 0; kb < 16; ++kb) {
        short8 a0 = *(const short8*)(asrc + ((kb * 2 + 0) * 64 + lane) * 8);
        short8 a1 = *(const short8*)(asrc + ((kb * 2 + 1) * 64 + lane) * 8);
        #pragma unroll
        for (int nf = 0; nf < 2; ++nf) {
          acc[0][nf] = __builtin_amdgcn_mfma_f32_16x16x32_bf16(a0, wr[kb][nf], acc[0][nf], 0, 0, 0);
          acc[1][nf] = __builtin_amdgcn_mfma_f32_16x16x32_bf16(a1, wr[kb][nf], acc[1][nf], 0, 0, 0);
        }
      }
      float* z = zbv + mm * 2144;
      #pragma unroll
      for (int mf = 0; mf < 2; ++mf)
        #pragma unroll
        for (int nf = 0; nf < 2; ++nf)
          #pragma unroll
          for (int q = 0; q < 4; ++q) {
            int row = mf * 16 + (lane >> 4) * 4 + q;
            int col = ch * 32 + nf * 16 + (lane & 15);
            z[row * 67 + col] = acc[mf][nf][q];
          }
    }
    __syncthreads();                     // Z-BAR

    // ---- combine: L0 on waves 0-3 || L1 on waves 4-5 ----
    const bool l0act = (r < T_STEPS);
    const bool l1act = (r >= 1 && r <= T_STEPS);
    if (tid < 256) {
      if (l0act) {                       // L0: 8 threads per sample, 2 units
        int m = tid >> 3, u0 = (tid & 7) << 1;
        float x0 = xtb[m * 4 + 0], x1 = xtb[m * 4 + 1], x2 = xtb[m * 4 + 2];
        float tmv = xtb[m * 4 + 3];
        unsigned pack = 0; float hnv[2];
        #pragma unroll
        for (int uu = 0; uu < 2; ++uu) {
          int u = u0 + uu;
          float zg[4];
          #pragma unroll
          for (int q = 0; q < 4; ++q) {
            int c = q * 16 + u;
            zg[q] = zbv[m * 67 + c] + prm[192 + c]
                  + x0 * prm[c] + x1 * prm[64 + c] + x2 * prm[128 + c];
          }
          float iv = sigm(zg[0]), fv = sigm(zg[1]), gv = tanh_f(zg[2]), ov = sigm(zg[3]);
          float cold = uu ? c0A1 : c0A0, hold = uu ? h0A1 : h0A0;
          float cp = fv * cold + iv * gv;
          float hp = ov * tanh_f(cp);
          float k = timegate(tmv, prm[448 + u], prm[464 + u]);
          float hn = k * hp + (1.f - k) * hold;
          float cn = k * cp + (1.f - k) * cold;
          if (uu) { h0A1 = hn; c0A1 = cn; } else { h0A0 = hn; c0A0 = cn; }
          hnv[uu] = hn;
          pack |= ((unsigned)(unsigned short)f2bf(hn)) << (16 * uu);
        }
        AT_ST((unsigned*)(P.H0b + ((size_t)bufB * 8 + g) * 16384 + fragidx(m, slice * 16 + u0)), pack);
        float sr = hnv[0] + hnv[1], qr = hnv[0] * hnv[0] + hnv[1] * hnv[1];
        sr += __shfl_down(sr, 4, 8); qr += __shfl_down(qr, 4, 8);
        sr += __shfl_down(sr, 2, 8); qr += __shfl_down(qr, 2, 8);
        sr += __shfl_down(sr, 1, 8); qr += __shfl_down(qr, 1, 8);
        if ((tid & 7) == 0) {
          ull pv = ((ull)__float_as_uint(qr) << 32) | __float_as_uint(sr);
          AT_ST((ull*)(P.St0 + ((size_t)bufB * 8 + g) * 2048) + m * 32 + slice, pv);
        }
      }
      // drain + arrival (unconditional); wave3 posts flag0 early
      asm volatile("s_waitcnt vmcnt(0)" ::: "memory");
      if (lane == 0) LDS_ADD(&tok[2]);
      if (wid == 3 && lane == 0) {
        const unsigned tgt = 4u * (unsigned)(r + 1);
        for (int it_ = 0; it_ < 2000000; ++it_) {
          if (LDS_LD(&tok[2]) >= tgt) break;
          __builtin_amdgcn_s_sleep(1);
        }
        if (r <= T_STEPS) AT_ST(P.flag0 + g * 32 + slice, (unsigned)(r + 1));
      }
    } else {
      if (l1act) {                       // L1: 4 threads per sample, 4 units
        int t = tid - 256;               // 0..127
        int m = t >> 2, j = t & 3;
        float mu0m = mus[m], rs0m = mus[32 + m];
        float tmv = xtb[128 + m];
        ull pack = 0;
        float s_ = 0.f, q_ = 0.f;
        #pragma unroll
        for (int uu = 0; uu < 4; ++uu) {
          int u = 4 * j + uu;
          float zg[4];
          #pragma unroll
          for (int q = 0; q < 4; ++q) {
            int c = q * 16 + u;
            float zA = zbv[2144 + m * 67 + c];   // h0 @ (g0.W1)
            float zB = zbv[4288 + m * 67 + c];   // h1 @ R1
            zg[q] = rs0m * zA + zB + prm[256 + c] - mu0m * rs0m * prm[320 + c];
          }
          float iv = sigm(zg[0]), fv = sigm(zg[1]), gv = tanh_f(zg[2]), ov = sigm(zg[3]);
          float cold = c1S[uu], hold = h1S[uu];
          float cp = fv * cold + iv * gv;
          float hp = ov * tanh_f(cp);
          float k = timegate(tmv, prm[480 + u], prm[496 + u]);
          float hn = k * hp + (1.f - k) * hold;
          float cn = k * cp + (1.f - k) * cold;
          h1S[uu] = hn; c1S[uu] = cn;
          s_ += hn; q_ += hn * hn;
          pack |= ((ull)(unsigned short)f2bf(hn)) << (16 * uu);
        }
        AT_ST((ull*)(P.H1b + ((size_t)bufA * 8 + g) * 16384 + fragidx(m, slice * 16 + 4 * j)), pack);
        s_ += __shfl_down(s_, 2, 4); q_ += __shfl_down(q_, 2, 4);
        s_ += __shfl_down(s_, 1, 4); q_ += __shfl_down(q_, 1, 4);
        if (j == 0) {
          ull pv = ((ull)__float_as_uint(q_) << 32) | __float_as_uint(s_);
          AT_ST((ull*)(P.St1 + ((size_t)bufA * 8 + g) * 2048) + m * 32 + slice, pv);
        }
      }
      // drain + arrival (unconditional); wave5 posts flag1
      asm volatile("s_waitcnt vmcnt(0)" ::: "memory");
      if (lane == 0) LDS_ADD(&tok[3]);
      if (wid == 5 && lane == 0) {
        const unsigned tgt = 2u * (unsigned)(r + 1);
        for (int it_ = 0; it_ < 2000000; ++it_) {
          if (LDS_LD(&tok[3]) >= tgt) break;
          __builtin_amdgcn_s_sleep(1);
        }
        if (r >= 1 && r <= T_STEPS) AT_ST(P.flag1 + g * 32 + slice, (unsigned)(r + 1));
      }
    }

    // ---- classifier head for step r-2 (wave 1; off critical path) ----
    if (wid == 1 && r >= 2) {
      int msam = slice;
      short8 hv8 = *(const short8*)(h1s + fragidx(msam, lane * 8));
      float lg[10];
      #pragma unroll
      for (int c = 0; c < 10; ++c) lg[c] = 0.f;
      #pragma unroll
      for (int kk = 0; kk < 8; ++kk) {
        float hv = bf2f(hv8[kk]);
        const float* wf = wfl + kk * 640 + lane;
        #pragma unroll
        for (int c = 0; c < 10; ++c) lg[c] += hv * wf[c * 64];
      }
      #pragma unroll
      for (int off = 32; off > 0; off >>= 1)
        #pragma unroll
        for (int c = 0; c < 10; ++c) lg[c] += __shfl_down(lg[c], off, 64);
      if (lane == 0) {
        float logit[10], mx = -1e30f;
        #pragma unroll
        for (int c = 0; c < 10; ++c) {
          logit[c] = r1r * lg[c] + ufl[c] - m1r * r1r * ufl[16 + c];
          mx = fmaxf(mx, logit[c]);
        }
        float ssum = 0.f;
        #pragma unroll
        for (int c = 0; c < 10; ++c) { logit[c] = expf(logit[c] - mx); ssum += logit[c]; }
        float inv = 1.f / ssum;
        float* op = P.out + ((size_t)(gm0 + msam) * T_STEPS + (r - 2)) * 10;
        #pragma unroll
        for (int c = 0; c < 10; ++c) op[c] = logit[c] * inv;
      }
    }
  }
}

extern "C" void kernel_launch(void* const* d_in, const int* in_sizes, int n_in,
                              void* d_out, int out_size, void* d_ws, size_t ws_size,
                              hipStream_t stream) {
  const float* x    = (const float*)d_in[0];
  const float* tms  = (const float*)d_in[1];
  const float* W0   = (const float*)d_in[2];
  const float* R0   = (const float*)d_in[3];
  const float* b0   = (const float*)d_in[4];
  const float* tau0 = (const float*)d_in[5];
  const float* s0   = (const float*)d_in[6];
  const float* g0   = (const float*)d_in[7];
  const float* be0  = (const float*)d_in[8];
  const float* W1   = (const float*)d_in[9];
  const float* R1   = (const float*)d_in[10];
  const float* b1   = (const float*)d_in[11];
  const float* tau1 = (const float*)d_in[12];
  const float* s1   = (const float*)d_in[13];
  const float* g1   = (const float*)d_in[14];
  const float* be1  = (const float*)d_in[15];
  const float* Wf   = (const float*)d_in[16];
  const float* bfv  = (const float*)d_in[17];

  char* ws = (char*)d_ws;
  short* Wswz = (short*)(ws + OFF_WSWZ);
  float* u1m  = (float*)(ws + OFF_U1);
  float* v1m  = (float*)(ws + OFF_V1);
  float* Wfpm = (float*)(ws + OFF_WFP);
  float* ufvm = (float*)(ws + OFF_UFV);

  Ptrs P;
  P.x = x; P.times = tms; P.W0 = W0; P.b0 = b0; P.tau0 = tau0; P.s0 = s0;
  P.b1 = b1; P.tau1 = tau1; P.s1 = s1;
  P.u1v = u1m; P.v1v = v1m; P.Wfp = Wfpm; P.ufv = ufvm;
  P.H0b = (short*)(ws + OFF_H0B);
  P.H1b = (short*)(ws + OFF_H1B);
  P.St0 = (float*)(ws + OFF_ST0);
  P.St1 = (float*)(ws + OFF_ST1);
  P.flag0 = (unsigned*)(ws + OFF_FLG0);
  P.flag1 = (unsigned*)(ws + OFF_FLG1);
  P.out = (float*)d_out;

  hipFuncSetAttribute(reinterpret_cast<const void*>(plstm_persist),
                      hipFuncAttributeMaxDynamicSharedMemorySize, SMEM_BYTES);

  prep_weights<<<1536, 256, 0, stream>>>(R0, W1, R1, g0, Wswz);
  prep_vecs<<<8, 256, 0, stream>>>(W1, g0, be0, u1m, v1m);
  prep_head<<<20, 256, 0, stream>>>(Wf, g1, be1, bfv, Wfpm, ufvm);
  hipMemsetAsync(ws + OFF_H0B, 0, ZERO_BYTES, stream);
  plstm_persist<<<NB, NTHR, SMEM_BYTES, stream>>>(P, Wswz);
}

// Round 16
// 5199.316 us; speedup vs baseline: 1.4461x; 1.4461x over previous
//
#include <hip/hip_runtime.h>
#include <hip/hip_bf16.h>

// PhasedLSTM classifier: persistent cooperative kernel (champion config, R9).
// 8 groups (32 samples) x 32 slices (16 units) = 256 blocks (1/CU).
// Cross-block exchange via relaxed agent-scope atomics (stores) and
// global_load_lds DMA with sc1 aux (loads) -> LDS, no VGPR round-trip.
// Sync: single per-slice monotonic round flag, wave0 poll + barrier.
// Round r computes L0 step r, L1 step r-1, head step r-2.

#define NB 256
#define NTHR 384
#define T_STEPS 500
#define RON 0.05f
#define ALPHA_LEAK 1e-3f

typedef short short8 __attribute__((ext_vector_type(8)));
typedef float f32x4 __attribute__((ext_vector_type(4)));
typedef unsigned long long ull;

// ---------------- ws layout (bytes) ----------------
#define OFF_WSWZ 0u              // 6291456  swizzled bf16 weights
#define OFF_U1   6291456u        // 8192
#define OFF_V1   6299648u        // 8192
#define OFF_WFP  6307840u        // 20480    Wf' permuted [kk][c][lane] f32
#define OFF_UFV  6328320u        // 128
#define OFF_H0B  6328448u        // 524288   [2][8][16384] bf16, frag order
#define OFF_H1B  6852736u        // 524288
#define OFF_ST0  7377024u        // 131072   [2][8][32 m][32 sl][2] f32
#define OFF_ST1  7508096u        // 131072
#define OFF_FLG0 7639168u        // 1024     [8][32] u32 round flags (unified)
#define OFF_FLG1 7640192u        // 1024     (unused, kept zeroed)
#define ZERO_BYTES 1312768u      // OFF_H0B .. OFF_FLG1+1024

// ---------------- LDS layout (bytes) ----------------
// 0      h0b            32768
// 32768  h1bL[2]        65536
// 98304  h0f/c0f/h1f/c1f 8192
// 106496 mu0/rs0/mu1/rs1  512
// 107008 zbv            25728   (3 x [32][67] f32)
// 132736 prm             2048
// 134784 wfl            20480   ([kk][c][64] f32, conflict-free)
// 155264 ufl              128
// 155392 xtb              512   ([32][4]: x0,x1,x2,t_r)
// 155904 xtb1             128   ([32]: t_{r-1})
#define SMEM_BYTES 156160

#define AT_LD(p)    __hip_atomic_load((p), __ATOMIC_RELAXED, __HIP_MEMORY_SCOPE_AGENT)
#define AT_ST(p, v) __hip_atomic_store((p), (v), __ATOMIC_RELAXED, __HIP_MEMORY_SCOPE_AGENT)

// global->LDS DMA, 16B/lane, aux=16 (CPol SCC == sc1, agent scope: L1 bypass,
// matching what AT_LD lowers to on gfx940+).
#define G2L(gp, lp) \
  __builtin_amdgcn_global_load_lds( \
      (const __attribute__((address_space(1))) void*)(gp), \
      (__attribute__((address_space(3))) void*)(lp), 16, 0, 16)

__device__ __forceinline__ short f2bf(float x) {
  unsigned u = __float_as_uint(x);
  unsigned r = (u + 0x7fffu + ((u >> 16) & 1u)) >> 16;
  return (short)r;
}
__device__ __forceinline__ float bf2f(short s) {
  return __uint_as_float(((unsigned)(unsigned short)s) << 16);
}
__device__ __forceinline__ float sigm(float x) { return 1.f / (1.f + __expf(-x)); }
__device__ __forceinline__ float tanh_f(float x) {
  float cx = fminf(fmaxf(x, -15.f), 15.f);
  float e = __expf(2.f * cx);
  return (e - 1.f) / (e + 1.f);
}
__device__ __forceinline__ float timegate(float t, float tau, float s) {
  float phi = fmodf(t - s, tau);
  if (phi < 0.f) phi += tau;
  phi /= tau;
  return phi < 0.5f * RON ? (2.f / RON) * phi
       : (phi < RON ? 2.f - (2.f / RON) * phi : ALPHA_LEAK * phi);
}
// element index (shorts) of (sample m, unit k) in a [32][512] bf16 buffer
// stored in 16x16x32-MFMA A-fragment order.
__device__ __forceinline__ int fragidx(int m, int k) {
  return ((((k >> 5) * 2 + (m >> 4)) * 64) + (((k >> 3) & 3) * 16) + (m & 15)) * 8 + (k & 7);
}

// ---------------- prep kernels ----------------
__global__ void prep_weights(const float* __restrict__ R0, const float* __restrict__ W1,
                             const float* __restrict__ R1, const float* __restrict__ g0,
                             short* __restrict__ Wswz) {
  int t = blockIdx.x * 256 + threadIdx.x;   // < 393216
  int lane = t & 63; int rest = t >> 6;
  int nf = rest & 1;  rest >>= 1;
  int kb = rest & 15; rest >>= 4;
  int ch = rest & 1;  rest >>= 1;
  int mm = rest % 3;  int slice = rest / 3;
  int c = ch * 32 + nf * 16 + (lane & 15);
  int gate = c >> 4;
  int unit = slice * 16 + (c & 15);
  int gcol = gate * 512 + unit;
  int k0 = kb * 32 + (lane >> 4) * 8;
  const float* src = (mm == 0) ? R0 : (mm == 1 ? W1 : R1);
  short8 o;
  #pragma unroll
  for (int e = 0; e < 8; ++e) {
    float v = src[(size_t)(k0 + e) * 2048 + gcol];
    if (mm == 1) v *= g0[k0 + e];
    o[e] = f2bf(v);
  }
  *(short8*)(Wswz + (size_t)t * 8) = o;
}

__global__ void prep_vecs(const float* __restrict__ W1, const float* __restrict__ g0,
                          const float* __restrict__ be0,
                          float* __restrict__ u1, float* __restrict__ v1) {
  int c = blockIdx.x * 256 + threadIdx.x;  // < 2048
  float su = 0.f, sv = 0.f;
  for (int k = 0; k < 512; ++k) {
    float w = W1[(size_t)k * 2048 + c];
    su += be0[k] * w; sv += g0[k] * w;
  }
  u1[c] = su; v1[c] = sv;
}

__global__ void prep_head(const float* __restrict__ Wf, const float* __restrict__ g1,
                          const float* __restrict__ be1, const float* __restrict__ bfv,
                          float* __restrict__ Wfp, float* __restrict__ ufv) {
  int t = blockIdx.x * 256 + threadIdx.x;
  if (t < 5120) {
    // permuted: t = kk*640 + c*64 + l, source k = 8l + kk
    int kk = t / 640, rem = t - kk * 640, c = rem >> 6, l = rem & 63;
    int k = 8 * l + kk;
    Wfp[t] = g1[k] * Wf[k * 10 + c];
  }
  if (t < 10) {
    float su = bfv[t], sv = 0.f;
    for (int k = 0; k < 512; ++k) {
      float w = Wf[k * 10 + t];
      su += be1[k] * w; sv += g1[k] * w;
    }
    ufv[t] = su; ufv[16 + t] = sv;
  }
}

// ---------------- persistent kernel ----------------
struct Ptrs {
  const float *x, *times, *W0, *b0, *tau0, *s0, *b1, *tau1, *s1;
  const float *u1v, *v1v, *Wfp, *ufv;
  short *H0b, *H1b;
  float *St0, *St1;
  unsigned *flag0, *flag1;
  float *out;
};

__launch_bounds__(NTHR, 1)
__global__ void plstm_persist(Ptrs P, const short* __restrict__ Wswz) {
  extern __shared__ char smem[];
  short* h0b  = (short*)smem;                 // staged h0 (32KB)
  short* h1bL = (short*)(smem + 32768);       // 2 slots x 32KB staged h1
  float* h0f  = (float*)(smem + 98304);
  float* c0f = h0f + 512;
  float* h1f = h0f + 1024;
  float* c1f = h0f + 1536;
  float* mu0 = (float*)(smem + 106496); float* rs0 = mu0 + 32;
  float* mu1 = mu0 + 64;                float* rs1 = mu0 + 96;
  float* zbv = (float*)(smem + 107008);       // 3 x [32][67]
  float* prm = (float*)(smem + 132736);       // 512 floats
  float* wfl = (float*)(smem + 134784);       // 5120 floats [kk][c][64]
  float* ufl = (float*)(smem + 155264);       // 32 floats
  float* xtb = (float*)(smem + 155392);       // [32][4]
  float* xtb1 = (float*)(smem + 155904);      // [32]

  const int tid = threadIdx.x;
  const int g = blockIdx.x & 7;
  const int slice = blockIdx.x >> 3;
  const int wid = tid >> 6, lane = tid & 63;
  const int mm = wid >> 1, ch = wid & 1;
  const int gm0 = g * 32;

  // ---- one-time LDS init: state zeros + params + head weights ----
  for (int i = tid; i < 2048; i += NTHR) h0f[i] = 0.f;
  for (int i = tid; i < 512; i += NTHR) {
    float v;
    if (i < 192)      { int f = i >> 6, c = i & 63; v = P.W0[f * 2048 + ((c >> 4) << 9) + slice * 16 + (c & 15)]; }
    else if (i < 256) { int c = i & 63; v = P.b0[((c >> 4) << 9) + slice * 16 + (c & 15)]; }
    else if (i < 320) { int c = i & 63; int gc = ((c >> 4) << 9) + slice * 16 + (c & 15);
                        v = P.b1[gc] + P.u1v[gc]; }
    else if (i < 384) { int c = i & 63; v = P.v1v[((c >> 4) << 9) + slice * 16 + (c & 15)]; }
    else if (i < 448) v = 0.f;
    else if (i < 464) v = P.tau0[slice * 16 + (i & 15)];
    else if (i < 480) v = P.s0[slice * 16 + (i & 15)];
    else if (i < 496) v = P.tau1[slice * 16 + (i & 15)];
    else              v = P.s1[slice * 16 + (i & 15)];
    prm[i] = v;
  }
  for (int i = tid; i < 5120; i += NTHR) wfl[i] = P.Wfp[i];
  if (tid < 32) ufl[tid] = P.ufv[tid];

  // ---- resident weights: 16 kb x 2 nf x short8 = 128 VGPRs ----
  short8 wr[16][2];
  {
    const short* wb = Wswz + ((((size_t)slice * 3 + mm) * 2 + ch) * 32 * 64) * 8;
    #pragma unroll
    for (int kb = 0; kb < 16; ++kb)
      #pragma unroll
      for (int nf = 0; nf < 2; ++nf) {
        wr[kb][nf] = *(const short8*)(wb + ((kb * 2 + nf) * 64 + lane) * 8);
        asm volatile("" : "+v"(wr[kb][nf]));   // value barrier vs remat
      }
  }
  __syncthreads();

  for (int r = 0; r <= T_STEPS + 1; ++r) {
    const int bufA = (r + 1) & 1;
    const int bufB = r & 1;
    short* h1s = h1bL + bufB * 16384;

    // ---- wave0: unified flag poll; wave4: x/times prefetch ----
    if (wid == 0) {
      const unsigned tgt = (unsigned)r;   // round r needs all producers @ r-1
      const unsigned* fp = P.flag0 + g * 32 + (lane & 31);
      for (int it_ = 0; it_ < 100000; ++it_) {
        unsigned v = (lane < 32) ? AT_LD(fp) : 0xFFFFFFFFu;
        if (__all((int)(v >= tgt))) break;
        __builtin_amdgcn_s_sleep(1);
      }
    } else if (wid == 4) {
      int m = lane & 31;
      if (lane < 32) {
        int step = (r < T_STEPS) ? r : (T_STEPS - 1);
        const float* xp = P.x + ((size_t)(gm0 + m) * T_STEPS + step) * 3;
        xtb[m * 4 + 0] = xp[0];
        xtb[m * 4 + 1] = xp[1];
        xtb[m * 4 + 2] = xp[2];
        xtb[m * 4 + 3] = P.times[(size_t)(gm0 + m) * T_STEPS + step];
      } else {
        int s1_ = (r >= 1) ? (r - 1) : 0;
        if (s1_ > T_STEPS - 1) s1_ = T_STEPS - 1;
        xtb1[m] = P.times[(size_t)(gm0 + m) * T_STEPS + s1_];
      }
    }
    __syncthreads();                     // poll-bar: flags confirmed block-wide

    // ---- stage: waves 0-3 DMA H -> LDS (16B/lane x16); wave5 stats ----
    if (tid < 256) {
      const char* gA = (const char*)(P.H0b + ((size_t)bufA * 8 + g) * 16384);
      const char* gB = (const char*)(P.H1b + ((size_t)bufB * 8 + g) * 16384);
      char* lA = (char*)h0b;
      char* lB = (char*)h1s;
      #pragma unroll
      for (int k = 0; k < 8; ++k) {
        size_t off = (size_t)(k * 256 + tid) * 16;
        G2L(gA + off, lA + off);
        G2L(gB + off, lB + off);
      }
    } else if (wid == 5) {   // LN stats finalize (lanes 0-31 L0, 32-63 L1)
      const int layer = lane >> 5, m = lane & 31;
      const float* base = layer ? (P.St1 + ((size_t)bufB * 8 + g) * 2048 + m * 64)
                                : (P.St0 + ((size_t)bufA * 8 + g) * 2048 + m * 64);
      const ull* bu = (const ull*)base;
      float s_ = 0.f, q_ = 0.f;
      #pragma unroll
      for (int sl = 0; sl < 32; ++sl) {
        ull v = AT_LD(bu + sl);
        s_ += __uint_as_float((unsigned)v);
        q_ += __uint_as_float((unsigned)(v >> 32));
      }
      float mu = s_ * (1.f / 512.f);
      float var = q_ * (1.f / 512.f) - mu * mu;
      float rs = rsqrtf(var + 1e-3f);
      if (layer == 0) { mu0[m] = mu; rs0[m] = rs; }
      else            { mu1[m] = mu; rs1[m] = rs; }
    }
    __syncthreads();                     // stage-bar: drains vmcnt (DMA) + lgkm
    float m1r = 0.f, r1r = 0.f;
    if (wid == 1) { m1r = mu1[slice]; r1r = rs1[slice]; }   // hoist for head

    // ---- MFMA: z-slice = A @ Wslice ----
    {
      f32x4 acc[2][2] = {};
      const short* asrc = (mm == 2) ? h1s : h0b;
      #pragma unroll
      for (int kb = 0; kb < 16; ++kb) {
        short8 a0 = *(const short8*)(asrc + ((kb * 2 + 0) * 64 + lane) * 8);
        short8 a1 = *(const short8*)(asrc + ((kb * 2 + 1) * 64 + lane) * 8);
        #pragma unroll
        for (int nf = 0; nf < 2; ++nf) {
          acc[0][nf] = __builtin_amdgcn_mfma_f32_16x16x32_bf16(a0, wr[kb][nf], acc[0][nf], 0, 0, 0);
          acc[1][nf] = __builtin_amdgcn_mfma_f32_16x16x32_bf16(a1, wr[kb][nf], acc[1][nf], 0, 0, 0);
        }
      }
      float* z = zbv + mm * 2144;
      #pragma unroll
      for (int mf = 0; mf < 2; ++mf)
        #pragma unroll
        for (int nf = 0; nf < 2; ++nf)
          #pragma unroll
          for (int q = 0; q < 4; ++q) {
            int row = mf * 16 + (lane >> 4) * 4 + q;
            int col = ch * 32 + nf * 16 + (lane & 15);
            z[row * 67 + col] = acc[mf][nf][q];
          }
    }
    __syncthreads();                     // z-bar

    // ---- combine: gates + cell/phase updates + fused LN partial stats ----
    const bool l0act = (r < T_STEPS);
    const bool l1act = (r >= 1 && r <= T_STEPS);
    if (tid < 256 && l0act) {            // layer 0: 8 threads per sample
      int m = tid >> 3, u0 = (tid & 7) << 1;
      float x0 = xtb[m * 4 + 0], x1 = xtb[m * 4 + 1], x2 = xtb[m * 4 + 2];
      float tmv = xtb[m * 4 + 3];
      unsigned pack = 0;
      float hnv[2];
      #pragma unroll
      for (int uu = 0; uu < 2; ++uu) {
        int u = u0 + uu, id = m * 16 + u;
        float zg4[4];
        #pragma unroll
        for (int q = 0; q < 4; ++q) {
          int c = q * 16 + u;
          zg4[q] = zbv[m * 67 + c] + prm[192 + c]
                 + x0 * prm[c] + x1 * prm[64 + c] + x2 * prm[128 + c];
        }
        float iv = sigm(zg4[0]), fv = sigm(zg4[1]), gv = tanh_f(zg4[2]), ov = sigm(zg4[3]);
        float cold = c0f[id], hold = h0f[id];
        float cp = fv * cold + iv * gv;
        float hp = ov * tanh_f(cp);
        float k = timegate(tmv, prm[448 + u], prm[464 + u]);
        float hn = k * hp + (1.f - k) * hold;
        float cn = k * cp + (1.f - k) * cold;
        h0f[id] = hn; c0f[id] = cn; hnv[uu] = hn;
        pack |= ((unsigned)(unsigned short)f2bf(hn)) << (16 * uu);
      }
      AT_ST((unsigned*)(P.H0b + ((size_t)bufB * 8 + g) * 16384 + fragidx(m, slice * 16 + u0)), pack);
      float sr = hnv[0] + hnv[1], qr = hnv[0] * hnv[0] + hnv[1] * hnv[1];
      sr += __shfl_down(sr, 4, 8); qr += __shfl_down(qr, 4, 8);
      sr += __shfl_down(sr, 2, 8); qr += __shfl_down(qr, 2, 8);
      sr += __shfl_down(sr, 1, 8); qr += __shfl_down(qr, 1, 8);
      if ((tid & 7) == 0) {
        ull pv = ((ull)__float_as_uint(qr) << 32) | __float_as_uint(sr);
        AT_ST((ull*)(P.St0 + ((size_t)bufB * 8 + g) * 2048) + m * 32 + slice, pv);
      }
    }
    #pragma unroll
    for (int pass = 0; pass < 2; ++pass) {  // layer 1 over 256 items on 384 thr
      int idx = -1;
      if (pass == 0 && tid >= 256) idx = tid - 256;
      if (pass == 1 && tid < 128)  idx = 128 + tid;
      if (idx >= 0 && l1act) {
        int m = idx >> 3, u0 = (idx & 7) << 1;
        float mu0m = mu0[m], rs0m = rs0[m];
        float tmv = xtb1[m];
        unsigned pack = 0;
        float hnv[2];
        #pragma unroll
        for (int uu = 0; uu < 2; ++uu) {
          int u = u0 + uu, id = m * 16 + u;
          float zg4[4];
          #pragma unroll
          for (int q = 0; q < 4; ++q) {
            int c = q * 16 + u;
            float zA = zbv[2144 + m * 67 + c];   // h0 @ (g0.W1)
            float zB = zbv[4288 + m * 67 + c];   // h1 @ R1
            zg4[q] = rs0m * zA + zB + prm[256 + c] - mu0m * rs0m * prm[320 + c];
          }
          float iv = sigm(zg4[0]), fv = sigm(zg4[1]), gv = tanh_f(zg4[2]), ov = sigm(zg4[3]);
          float cold = c1f[id], hold = h1f[id];
          float cp = fv * cold + iv * gv;
          float hp = ov * tanh_f(cp);
          float k = timegate(tmv, prm[480 + u], prm[496 + u]);
          float hn = k * hp + (1.f - k) * hold;
          float cn = k * cp + (1.f - k) * cold;
          h1f[id] = hn; c1f[id] = cn; hnv[uu] = hn;
          pack |= ((unsigned)(unsigned short)f2bf(hn)) << (16 * uu);
        }
        AT_ST((unsigned*)(P.H1b + ((size_t)bufA * 8 + g) * 16384 + fragidx(m, slice * 16 + u0)), pack);
        float sr = hnv[0] + hnv[1], qr = hnv[0] * hnv[0] + hnv[1] * hnv[1];
        sr += __shfl_down(sr, 4, 8); qr += __shfl_down(qr, 4, 8);
        sr += __shfl_down(sr, 2, 8); qr += __shfl_down(qr, 2, 8);
        sr += __shfl_down(sr, 1, 8); qr += __shfl_down(qr, 1, 8);
        if ((idx & 7) == 0) {
          ull pv = ((ull)__float_as_uint(qr) << 32) | __float_as_uint(sr);
          AT_ST((ull*)(P.St1 + ((size_t)bufA * 8 + g) * 2048) + m * 32 + slice, pv);
        }
      }
    }
    __syncthreads();   // combine-bar: vmcnt drained -> all H/St stores visible

    // ---- unified flag post (head overlaps next round's poll) ----
    if (tid == 0 && r <= T_STEPS) {
      AT_ST(P.flag0 + g * 32 + slice, (unsigned)(r + 1));
    }
    // ---- classifier head for step r-2 (wave 1; overlaps next round) ----
    if (wid == 1 && r >= 2) {
      int msam = slice;
      short8 hv8 = *(const short8*)(h1s + fragidx(msam, lane * 8));
      float lg[10];
      #pragma unroll
      for (int c = 0; c < 10; ++c) lg[c] = 0.f;
      #pragma unroll
      for (int kk = 0; kk < 8; ++kk) {
        float hv = bf2f(hv8[kk]);
        const float* wf = wfl + kk * 640 + lane;
        #pragma unroll
        for (int c = 0; c < 10; ++c) lg[c] += hv * wf[c * 64];
      }
      #pragma unroll
      for (int off = 32; off > 0; off >>= 1)
        #pragma unroll
        for (int c = 0; c < 10; ++c) lg[c] += __shfl_down(lg[c], off, 64);
      if (lane == 0) {
        float logit[10], mx = -1e30f;
        #pragma unroll
        for (int c = 0; c < 10; ++c) {
          logit[c] = r1r * lg[c] + ufl[c] - m1r * r1r * ufl[16 + c];
          mx = fmaxf(mx, logit[c]);
        }
        float ssum = 0.f;
        #pragma unroll
        for (int c = 0; c < 10; ++c) { logit[c] = expf(logit[c] - mx); ssum += logit[c]; }
        float inv = 1.f / ssum;
        float* op = P.out + ((size_t)(gm0 + msam) * T_STEPS + (r - 2)) * 10;
        #pragma unroll
        for (int c = 0; c < 10; ++c) op[c] = logit[c] * inv;
      }
    }
  }
}

extern "C" void kernel_launch(void* const* d_in, const int* in_sizes, int n_in,
                              void* d_out, int out_size, void* d_ws, size_t ws_size,
                              hipStream_t stream) {
  const float* x    = (const float*)d_in[0];
  const float* tms  = (const float*)d_in[1];
  const float* W0   = (const float*)d_in[2];
  const float* R0   = (const float*)d_in[3];
  const float* b0   = (const float*)d_in[4];
  const float* tau0 = (const float*)d_in[5];
  const float* s0   = (const float*)d_in[6];
  const float* g0   = (const float*)d_in[7];
  const float* be0  = (const float*)d_in[8];
  const float* W1   = (const float*)d_in[9];
  const float* R1   = (const float*)d_in[10];
  const float* b1   = (const float*)d_in[11];
  const float* tau1 = (const float*)d_in[12];
  const float* s1   = (const float*)d_in[13];
  const float* g1   = (const float*)d_in[14];
  const float* be1  = (const float*)d_in[15];
  const float* Wf   = (const float*)d_in[16];
  const float* bfv  = (const float*)d_in[17];

  char* ws = (char*)d_ws;
  short* Wswz = (short*)(ws + OFF_WSWZ);
  float* u1m  = (float*)(ws + OFF_U1);
  float* v1m  = (float*)(ws + OFF_V1);
  float* Wfpm = (float*)(ws + OFF_WFP);
  float* ufvm = (float*)(ws + OFF_UFV);

  Ptrs P;
  P.x = x; P.times = tms; P.W0 = W0; P.b0 = b0; P.tau0 = tau0; P.s0 = s0;
  P.b1 = b1; P.tau1 = tau1; P.s1 = s1;
  P.u1v = u1m; P.v1v = v1m; P.Wfp = Wfpm; P.ufv = ufvm;
  P.H0b = (short*)(ws + OFF_H0B);
  P.H1b = (short*)(ws + OFF_H1B);
  P.St0 = (float*)(ws + OFF_ST0);
  P.St1 = (float*)(ws + OFF_ST1);
  P.flag0 = (unsigned*)(ws + OFF_FLG0);
  P.flag1 = (unsigned*)(ws + OFF_FLG1);
  P.out = (float*)d_out;

  hipFuncSetAttribute(reinterpret_cast<const void*>(plstm_persist),
                      hipFuncAttributeMaxDynamicSharedMemorySize, SMEM_BYTES);

  prep_weights<<<1536, 256, 0, stream>>>(R0, W1, R1, g0, Wswz);
  prep_vecs<<<8, 256, 0, stream>>>(W1, g0, be0, u1m, v1m);
  prep_head<<<20, 256, 0, stream>>>(Wf, g1, be1, bfv, Wfpm, ufvm);
  hipMemsetAsync(ws + OFF_H0B, 0, ZERO_BYTES, stream);
  plstm_persist<<<NB, NTHR, SMEM_BYTES, stream>>>(P, Wswz);
}